// Round 2
// baseline (468.123 us; speedup 1.0000x reference)
//
#include <hip/hip_runtime.h>

#define NN 4096     // nodes
#define HC 8        // heads
#define DC 32       // dim per head
#define OC 256      // out channels = HC*DC
#define KC 256      // in channels
#define CF 6        // curvature features

typedef __bf16 bf16_t;
typedef bf16_t bf16x8 __attribute__((ext_vector_type(8)));
typedef float f32x4 __attribute__((ext_vector_type(4)));
typedef float f32x2 __attribute__((ext_vector_type(2)));
typedef int i32x4 __attribute__((ext_vector_type(4)));

#if defined(__has_builtin)
#if __has_builtin(__builtin_amdgcn_exp2f)
#define EXP2F(x) __builtin_amdgcn_exp2f(x)
#else
#define EXP2F(x) exp2f(x)
#endif
#else
#define EXP2F(x) exp2f(x)
#endif

// ---------------------------------------------------------------------------
// Kernel 1: fused h-GEMM + e_l/e_r dots + bf16 transposed V store.
// Tile: 64 i-rows x 32 cols (= exactly one head). Grid (64, 8) = 512 blocks,
// 256 threads (2 blocks/CU). Per-thread 2x4 micro-tile.
// Epilogue: e_l2[i,h] / e_r2T[h][i] via 8-lane shuffle reduce of acc . a_{l,r};
// hT2 written in the attn B-fragment layout [head][chunk32][quad][d32][t8]
// via an LDS transpose so attn's V loads are wave-contiguous.
// fp32 h is never materialized (attn only consumes bf16 hT2).
// ---------------------------------------------------------------------------
__global__ __launch_bounds__(256) void gemm_fused(const float* __restrict__ x,
                                                  const float* __restrict__ W,
                                                  const float* __restrict__ a_l,
                                                  const float* __restrict__ a_r,
                                                  float* __restrict__ e_l2,
                                                  float* __restrict__ e_r2T,
                                                  bf16_t* __restrict__ hT2) {
  __shared__ float As[16][68];   // [k][i]
  __shared__ float Bs[16][36];   // [k][c]
  __shared__ float Ct[DC][65];   // [c][i] transpose staging
  const float LOG2E = 1.44269504088896340736f;
  const int t = threadIdx.x;
  const int i0 = blockIdx.x * 64;
  const int head = blockIdx.y;
  const int c0 = head * DC;
  const int tx = t & 7;          // col group (4 cols)
  const int ty = t >> 3;         // row pair (2 rows)
  const int lr = t >> 2;         // staging row 0..63
  const int lk = (t & 3) * 4;    // staging k 0,4,8,12

  float acc[2][4] = {};
  for (int kk = 0; kk < KC; kk += 16) {
    f32x4 av = *(const f32x4*)&x[(size_t)(i0 + lr) * KC + kk + lk];
    f32x4 wv;
    if (t < 128) wv = *(const f32x4*)&W[(size_t)(c0 + (t >> 2)) * KC + kk + lk];
    __syncthreads();
    As[lk + 0][lr] = av[0]; As[lk + 1][lr] = av[1];
    As[lk + 2][lr] = av[2]; As[lk + 3][lr] = av[3];
    if (t < 128) {
      int br = t >> 2;
      Bs[lk + 0][br] = wv[0]; Bs[lk + 1][br] = wv[1];
      Bs[lk + 2][br] = wv[2]; Bs[lk + 3][br] = wv[3];
    }
    __syncthreads();
#pragma unroll
    for (int k = 0; k < 16; ++k) {
      f32x2 a = *(const f32x2*)&As[k][ty * 2];
      f32x4 b = *(const f32x4*)&Bs[k][tx * 4];
#pragma unroll
      for (int r = 0; r < 2; ++r)
#pragma unroll
        for (int u = 0; u < 4; ++u)
          acc[r][u] += a[r] * b[u];
    }
  }

  // e_l / e_r: dot acc rows with a_l/a_r slices, reduce across the 8 tx lanes
  f32x4 al4 = *(const f32x4*)&a_l[c0 + tx * 4];
  f32x4 ar4 = *(const f32x4*)&a_r[c0 + tx * 4];
#pragma unroll
  for (int r = 0; r < 2; ++r) {
    float el = acc[r][0] * al4[0] + acc[r][1] * al4[1] +
               acc[r][2] * al4[2] + acc[r][3] * al4[3];
    float er = acc[r][0] * ar4[0] + acc[r][1] * ar4[1] +
               acc[r][2] * ar4[2] + acc[r][3] * ar4[3];
    el += __shfl_xor(el, 1, 64); el += __shfl_xor(el, 2, 64); el += __shfl_xor(el, 4, 64);
    er += __shfl_xor(er, 1, 64); er += __shfl_xor(er, 2, 64); er += __shfl_xor(er, 4, 64);
    if (tx == 0) {
      int i = i0 + ty * 2 + r;
      e_l2[i * HC + head] = el * LOG2E;
      e_r2T[head * NN + i] = er * LOG2E;
    }
  }

  // transpose to B-fragment layout via LDS
#pragma unroll
  for (int r = 0; r < 2; ++r)
#pragma unroll
    for (int u = 0; u < 4; ++u)
      Ct[tx * 4 + u][ty * 2 + r] = acc[r][u];
  __syncthreads();
  // hT2 linear layout: head*131072 + chunk*1024 + quad*256 + d*8 + t8
  const size_t base = (size_t)head * (NN / 32) * 1024 + (size_t)blockIdx.x * 2048;
#pragma unroll
  for (int rep = 0; rep < 8; ++rep) {
    int idx = rep * 256 + t;                 // enumerates [chunkL][q][d][t8]
    int dd = (idx >> 3) & 31;
    int jl = (idx >> 10) * 32 + ((idx >> 8) & 3) * 8 + (idx & 7);
    hT2[base + idx] = (bf16_t)Ct[dd][jl];
  }
}

// ---------------------------------------------------------------------------
// Kernel 2: pack adj (64 MB int) -> 2 MB bitmask adjb[i*128 + c] (bit b of
// word c = adj[i][c*32+b] > 0). Also folds in the tiny cfT transpose and
// Wc2 = Wc * gate * log2e precompute. HBM-bound (~64 MB read).
// ---------------------------------------------------------------------------
__global__ __launch_bounds__(256) void pack(const int* __restrict__ adj,
                                            const float* __restrict__ cfeat,
                                            const float* __restrict__ Wc,
                                            const float* __restrict__ gate,
                                            unsigned* __restrict__ adjb,
                                            float* __restrict__ cfT,
                                            float* __restrict__ Wc2) {
  const float LOG2E = 1.44269504088896340736f;
  const int tid = blockIdx.x * 256 + threadIdx.x;   // 0 .. 524287
  {
    const int i = tid >> 7, c = tid & 127;
    const int* p = adj + (size_t)i * NN + c * 32;
    unsigned m = 0;
#pragma unroll
    for (int u = 0; u < 8; ++u) {
      i32x4 v = *(const i32x4*)(p + u * 4);
#pragma unroll
      for (int q = 0; q < 4; ++q) m |= (v[q] > 0 ? 1u : 0u) << (u * 4 + q);
    }
    adjb[tid] = m;
  }
  if (tid < NN * CF) {
    int j = tid / CF, f = tid - j * CF;
    cfT[f * NN + j] = cfeat[tid];
  }
  if (tid < HC * CF) Wc2[tid] = Wc[tid] * gate[0] * LOG2E;
}

// ---------------------------------------------------------------------------
// Kernel 3: fused masked attention.
// Grid: 256 blocks (16 i-rows) x 1024 threads (16 waves -> 50% occupancy cap;
// VGPR must stay <=128, hence __launch_bounds__(1024,4)).
// Wave w handles j-chunks {w, w+16, ...} of 32 j's; all 8 heads.
// P built directly in MFMA A-fragment layout; V read from hT2 in B-fragment
// layout (wave-contiguous 16B/lane). No online max (logits bounded; masked
// p == 0 exactly), so j-chunks combine by plain addition.
// ---------------------------------------------------------------------------
__global__ __launch_bounds__(1024, 4) void attn(const unsigned* __restrict__ adjb,
                                                const float* __restrict__ e_l2,
                                                const float* __restrict__ e_r2T,
                                                const float* __restrict__ cfT,
                                                const float* __restrict__ Wc2,
                                                const bf16_t* __restrict__ hT2,
                                                float* __restrict__ out) {
  __shared__ float Obuf[16][OC];
  __shared__ float Sbuf[16][HC];
  const int tid = threadIdx.x;
  const int w = tid >> 6;        // 0..15
  const int lane = tid & 63;
  const int il = lane & 15;
  const int quad = lane >> 4;
  const int ibase = blockIdx.x * 16;
  const int i = ibase + il;

  for (int idx = tid; idx < 16 * OC; idx += 1024) (&Obuf[0][0])[idx] = 0.f;
  if (tid < 16 * HC) (&Sbuf[0][0])[tid] = 0.f;
  __syncthreads();

  float cfi[CF];
#pragma unroll
  for (int f = 0; f < CF; ++f) cfi[f] = cfT[f * NN + i];
  float el[HC];
  {
    f32x4 e0 = *(const f32x4*)&e_l2[i * HC];
    f32x4 e1 = *(const f32x4*)&e_l2[i * HC + 4];
#pragma unroll
    for (int u = 0; u < 4; ++u) { el[u] = e0[u]; el[4 + u] = e1[u]; }
  }
  float wc[HC][CF];
#pragma unroll
  for (int q = 0; q < HC * CF; ++q) (&wc[0][0])[q] = Wc2[q];  // uniform -> SGPRs

  f32x4 acc[HC][2];
#pragma unroll
  for (int hh = 0; hh < HC; ++hh)
#pragma unroll
    for (int d = 0; d < 2; ++d) acc[hh][d] = (f32x4){0.f, 0.f, 0.f, 0.f};
  float S[HC] = {};

  for (int c = w; c < NN / 32; c += 16) {
    const int jq = c * 32 + quad * 8;
    // adjacency bits for this lane's row, 8 j's (one dword from 2MB L2-hot buf)
    const unsigned m8 = (adjb[i * 128 + c] >> (quad * 8)) & 0xffu;
    float mf[8];
#pragma unroll
    for (int tt = 0; tt < 8; ++tt) mf[tt] = ((m8 >> tt) & 1u) ? 1.f : 0.f;
    // |cf_i - cf_j| for 8 j's
    float ad[CF][8];
#pragma unroll
    for (int f = 0; f < CF; ++f) {
      f32x4 c0v = *(const f32x4*)&cfT[f * NN + jq];
      f32x4 c1v = *(const f32x4*)&cfT[f * NN + jq + 4];
#pragma unroll
      for (int u = 0; u < 4; ++u) {
        ad[f][u] = fabsf(cfi[f] - c0v[u]);
        ad[f][4 + u] = fabsf(cfi[f] - c1v[u]);
      }
    }
#pragma unroll
    for (int hh = 0; hh < HC; ++hh) {
      f32x4 er0 = *(const f32x4*)&e_r2T[hh * NN + jq];
      f32x4 er1 = *(const f32x4*)&e_r2T[hh * NN + jq + 4];
      float er[8];
#pragma unroll
      for (int u = 0; u < 4; ++u) { er[u] = er0[u]; er[4 + u] = er1[u]; }
      bf16x8 af;
#pragma unroll
      for (int tt = 0; tt < 8; ++tt) {
        float s = el[hh] + er[tt];
        float l = fmaxf(s, 0.2f * s);       // log2e-scaled leaky_relu
        float arg = l;
#pragma unroll
        for (int f = 0; f < CF; ++f) arg += ad[f][tt] * wc[hh][f];
        float pv = EXP2F(arg) * mf[tt];
        S[hh] += pv;
        af[tt] = (bf16_t)pv;
      }
      const bf16_t* bp = hT2 + (size_t)hh * ((NN / 32) * 1024) + c * 1024 + quad * 256 + il * 8;
      bf16x8 b0 = *(const bf16x8*)bp;            // d = il
      bf16x8 b1 = *(const bf16x8*)(bp + 128);    // d = il + 16
      acc[hh][0] = __builtin_amdgcn_mfma_f32_16x16x32_bf16(af, b0, acc[hh][0], 0, 0, 0);
      acc[hh][1] = __builtin_amdgcn_mfma_f32_16x16x32_bf16(af, b1, acc[hh][1], 0, 0, 0);
    }
  }

  // reduce S across the 4 quads (lanes il, il+16, il+32, il+48)
#pragma unroll
  for (int hh = 0; hh < HC; ++hh) {
    float v = S[hh];
    v += __shfl_xor(v, 16, 64);
    v += __shfl_xor(v, 32, 64);
    S[hh] = v;
  }
  if (quad == 0) {
#pragma unroll
    for (int hh = 0; hh < HC; ++hh) atomicAdd(&Sbuf[il][hh], S[hh]);
  }
  // accumulate O partials: C/D layout row = quad*4+r (i), col = il (d half)
#pragma unroll
  for (int hh = 0; hh < HC; ++hh)
#pragma unroll
    for (int dh = 0; dh < 2; ++dh)
#pragma unroll
      for (int r = 0; r < 4; ++r)
        atomicAdd(&Obuf[quad * 4 + r][hh * DC + dh * 16 + il], acc[hh][dh][r]);
  __syncthreads();

  // epilogue: divide by softmax denom, coalesced store
  for (int idx = tid; idx < 16 * OC; idx += 1024) {
    int row = idx >> 8;
    int hd = idx & 255;
    out[(size_t)(ibase + row) * OC + hd] = Obuf[row][hd] / Sbuf[row][hd >> 5];
  }
}

// ---------------------------------------------------------------------------
extern "C" void kernel_launch(void* const* d_in, const int* in_sizes, int n_in,
                              void* d_out, int out_size, void* d_ws, size_t ws_size,
                              hipStream_t stream) {
  const float* x    = (const float*)d_in[0];
  // d_in[1] = positions — unused by the reference
  const float* cfeat= (const float*)d_in[2];
  const int*   adj  = (const int*)d_in[3];
  const float* W    = (const float*)d_in[4];
  const float* a_l  = (const float*)d_in[5];
  const float* a_r  = (const float*)d_in[6];
  const float* Wc   = (const float*)d_in[7];
  const float* gate = (const float*)d_in[8];
  float* out = (float*)d_out;

  char* ws = (char*)d_ws;
  bf16_t*   hT2  = (bf16_t*)ws;                              // 2 MB
  unsigned* adjb = (unsigned*)(ws + (2u << 20));             // 2 MB
  float*    e_l2 = (float*)(ws + (4u << 20));                // 128 KB
  float*    e_r2T= (float*)(ws + (4u << 20) + (128u << 10)); // 128 KB
  float*    cfT  = (float*)(ws + (4u << 20) + (256u << 10)); // 96 KB
  float*    Wc2  = (float*)(ws + (4u << 20) + (384u << 10)); // 192 B

  gemm_fused<<<dim3(NN / 64, HC), 256, 0, stream>>>(x, W, a_l, a_r, e_l2, e_r2T, hT2);
  pack<<<(NN * NN / 32) / 256, 256, 0, stream>>>(adj, cfeat, Wc, gate, adjb, cfT, Wc2);
  attn<<<NN / 16, 1024, 0, stream>>>(adjb, e_l2, e_r2T, cfT, Wc2, hT2, out);
}

// Round 3
// 252.701 us; speedup vs baseline: 1.8525x; 1.8525x over previous
//
#include <hip/hip_runtime.h>

#define NN 4096     // nodes
#define HC 8        // heads
#define DC 32       // dim per head
#define OC 256      // out channels = HC*DC
#define KC 256      // in channels
#define CF 6        // curvature features

typedef __bf16 bf16_t;
typedef bf16_t bf16x8 __attribute__((ext_vector_type(8)));
typedef float f32x4 __attribute__((ext_vector_type(4)));
typedef float f32x2 __attribute__((ext_vector_type(2)));
typedef int i32x4 __attribute__((ext_vector_type(4)));

#if defined(__has_builtin)
#if __has_builtin(__builtin_amdgcn_exp2f)
#define EXP2F(x) __builtin_amdgcn_exp2f(x)
#else
#define EXP2F(x) exp2f(x)
#endif
#else
#define EXP2F(x) exp2f(x)
#endif

// ---------------------------------------------------------------------------
// Kernel 1: fused h-GEMM + e_l/e_r dots + bf16 transposed V store.
// Tile: 64 i-rows x 32 cols (= one head). Grid (64, 8), 256 threads.
// hT2 layout: [head][chunk32][quad][d32][t8] so attn V loads are
// wave-contiguous 16 B/lane. fp32 h never materialized.
// ---------------------------------------------------------------------------
__global__ __launch_bounds__(256) void gemm_fused(const float* __restrict__ x,
                                                  const float* __restrict__ W,
                                                  const float* __restrict__ a_l,
                                                  const float* __restrict__ a_r,
                                                  float* __restrict__ e_l2,
                                                  float* __restrict__ e_r2T,
                                                  bf16_t* __restrict__ hT2) {
  __shared__ float As[16][68];   // [k][i]
  __shared__ float Bs[16][36];   // [k][c]
  __shared__ float Ct[DC][65];   // [c][i] transpose staging
  const float LOG2E = 1.44269504088896340736f;
  const int t = threadIdx.x;
  const int i0 = blockIdx.x * 64;
  const int head = blockIdx.y;
  const int c0 = head * DC;
  const int tx = t & 7;          // col group (4 cols)
  const int ty = t >> 3;         // row pair (2 rows)
  const int lr = t >> 2;         // staging row 0..63
  const int lk = (t & 3) * 4;    // staging k 0,4,8,12

  float acc[2][4] = {};
  for (int kk = 0; kk < KC; kk += 16) {
    f32x4 av = *(const f32x4*)&x[(size_t)(i0 + lr) * KC + kk + lk];
    f32x4 wv;
    if (t < 128) wv = *(const f32x4*)&W[(size_t)(c0 + (t >> 2)) * KC + kk + lk];
    __syncthreads();
    As[lk + 0][lr] = av[0]; As[lk + 1][lr] = av[1];
    As[lk + 2][lr] = av[2]; As[lk + 3][lr] = av[3];
    if (t < 128) {
      int br = t >> 2;
      Bs[lk + 0][br] = wv[0]; Bs[lk + 1][br] = wv[1];
      Bs[lk + 2][br] = wv[2]; Bs[lk + 3][br] = wv[3];
    }
    __syncthreads();
#pragma unroll
    for (int k = 0; k < 16; ++k) {
      f32x2 a = *(const f32x2*)&As[k][ty * 2];
      f32x4 b = *(const f32x4*)&Bs[k][tx * 4];
#pragma unroll
      for (int r = 0; r < 2; ++r)
#pragma unroll
        for (int u = 0; u < 4; ++u)
          acc[r][u] += a[r] * b[u];
    }
  }

  // e_l / e_r dots, reduce across the 8 tx lanes
  f32x4 al4 = *(const f32x4*)&a_l[c0 + tx * 4];
  f32x4 ar4 = *(const f32x4*)&a_r[c0 + tx * 4];
#pragma unroll
  for (int r = 0; r < 2; ++r) {
    float el = acc[r][0] * al4[0] + acc[r][1] * al4[1] +
               acc[r][2] * al4[2] + acc[r][3] * al4[3];
    float er = acc[r][0] * ar4[0] + acc[r][1] * ar4[1] +
               acc[r][2] * ar4[2] + acc[r][3] * ar4[3];
    el += __shfl_xor(el, 1, 64); el += __shfl_xor(el, 2, 64); el += __shfl_xor(el, 4, 64);
    er += __shfl_xor(er, 1, 64); er += __shfl_xor(er, 2, 64); er += __shfl_xor(er, 4, 64);
    if (tx == 0) {
      int i = i0 + ty * 2 + r;
      e_l2[i * HC + head] = el * LOG2E;
      e_r2T[head * NN + i] = er * LOG2E;
    }
  }

  // transpose to B-fragment layout via LDS
#pragma unroll
  for (int r = 0; r < 2; ++r)
#pragma unroll
    for (int u = 0; u < 4; ++u)
      Ct[tx * 4 + u][ty * 2 + r] = acc[r][u];
  __syncthreads();
  const size_t base = (size_t)head * (NN / 32) * 1024 + (size_t)blockIdx.x * 2048;
#pragma unroll
  for (int rep = 0; rep < 8; ++rep) {
    int idx = rep * 256 + t;                 // enumerates [chunkL][q][d][t8]
    int dd = (idx >> 3) & 31;
    int jl = (idx >> 10) * 32 + ((idx >> 8) & 3) * 8 + (idx & 7);
    hT2[base + idx] = (bf16_t)Ct[dd][jl];
  }
}

// ---------------------------------------------------------------------------
// Kernel 2: ballot-pack adj (64 MB) -> 2 MB bitmask. Each wave reads 64
// consecutive ints (1 coalesced dword/lane), __ballot -> 64-bit mask, lane 0
// stores it. Layout identical to before: bit b of word adjb[i*128+c] =
// adj[i][c*32+b] > 0. Also folds cfT transpose + Wc2 precompute.
// ---------------------------------------------------------------------------
__global__ __launch_bounds__(256) void pack(const int* __restrict__ adj,
                                            const float* __restrict__ cfeat,
                                            const float* __restrict__ Wc,
                                            const float* __restrict__ gate,
                                            unsigned* __restrict__ adjb,
                                            float* __restrict__ cfT,
                                            float* __restrict__ Wc2) {
  const float LOG2E = 1.44269504088896340736f;
  const int tid = blockIdx.x * 256 + threadIdx.x;
  const int lane = threadIdx.x & 63;
  const int wv = (blockIdx.x * 4) + (threadIdx.x >> 6);  // global wave id, 0..8191
  // each wave: 32 segments of 64 consecutive elements
  for (int it = 0; it < 32; ++it) {
    int g = wv * 32 + it;            // segment id, 0..262143
    int i = g >> 6;                  // row
    int s = g & 63;                  // 64-elem segment within row
    int v = adj[(size_t)i * NN + s * 64 + lane];
    unsigned long long m = __ballot(v > 0);
    if (lane == 0) *(unsigned long long*)(adjb + i * 128 + s * 2) = m;
  }
  if (tid < NN * CF) {
    int j = tid / CF, f = tid - j * CF;
    cfT[f * NN + j] = cfeat[tid];
  }
  if (tid < HC * CF) Wc2[tid] = Wc[tid] * gate[0] * LOG2E;
}

// ---------------------------------------------------------------------------
// Kernel 3: fused masked attention, 4 heads per block.
// Grid: (NN/16, 2) = 512 blocks x 512 threads (8 waves) -> 2 blocks/CU,
// 16 waves/CU. __launch_bounds__(512,4) caps 128 regs/wave; live set:
// acc 32 (AGPR) + arg 32 + ad/mf/temps ~50 -> fits without spill.
// Wave w handles j-chunks {w, w+8, ...}; P built in MFMA A-frag layout;
// V read from hT2 in B-frag layout. No online max (logits bounded, masked
// p == 0 exactly) so partials combine by plain addition.
// ---------------------------------------------------------------------------
__global__ __launch_bounds__(512, 4) void attn(const unsigned* __restrict__ adjb,
                                               const float* __restrict__ e_l2,
                                               const float* __restrict__ e_r2T,
                                               const float* __restrict__ cfT,
                                               const float* __restrict__ Wc2,
                                               const bf16_t* __restrict__ hT2,
                                               float* __restrict__ out) {
  __shared__ float Obuf[16][128];
  __shared__ float Sbuf[16][4];
  const int tid = threadIdx.x;
  const int w = tid >> 6;        // 0..7
  const int lane = tid & 63;
  const int il = lane & 15;
  const int quad = lane >> 4;
  const int ibase = blockIdx.x * 16;
  const int hg = blockIdx.y;     // head group: heads hg*4 .. hg*4+3
  const int i = ibase + il;

  for (int idx = tid; idx < 16 * 128; idx += 512) (&Obuf[0][0])[idx] = 0.f;
  if (tid < 64) (&Sbuf[0][0])[tid] = 0.f;
  __syncthreads();

  float cfi[CF];
#pragma unroll
  for (int f = 0; f < CF; ++f) cfi[f] = cfT[f * NN + i];
  float el[4];
  {
    f32x4 e0 = *(const f32x4*)&e_l2[i * HC + hg * 4];
#pragma unroll
    for (int u = 0; u < 4; ++u) el[u] = e0[u];
  }
  float wc[4][CF];
#pragma unroll
  for (int h = 0; h < 4; ++h)
#pragma unroll
    for (int f = 0; f < CF; ++f) wc[h][f] = Wc2[(hg * 4 + h) * CF + f];

  f32x4 acc[4][2];
#pragma unroll
  for (int h = 0; h < 4; ++h)
#pragma unroll
    for (int d = 0; d < 2; ++d) acc[h][d] = (f32x4){0.f, 0.f, 0.f, 0.f};
  float S[4] = {};

  const bf16_t* hTbase = hT2 + (size_t)hg * 4 * ((NN / 32) * 1024) + quad * 256 + il * 8;

  for (int c = w; c < NN / 32; c += 8) {
    const int jq = c * 32 + quad * 8;
    const unsigned m8 = (adjb[i * 128 + c] >> (quad * 8)) & 0xffu;
    float mf[8];
#pragma unroll
    for (int tt = 0; tt < 8; ++tt) mf[tt] = ((m8 >> tt) & 1u) ? 1.f : 0.f;

    // arg[h][tt] = leaky(el+er) (log2e-scaled), then += |cf_i-cf_j|*wc
    float arg[4][8];
#pragma unroll
    for (int h = 0; h < 4; ++h) {
      f32x4 er0 = *(const f32x4*)&e_r2T[(hg * 4 + h) * NN + jq];
      f32x4 er1 = *(const f32x4*)&e_r2T[(hg * 4 + h) * NN + jq + 4];
#pragma unroll
      for (int u = 0; u < 4; ++u) {
        float s0 = el[h] + er0[u];
        float s1 = el[h] + er1[u];
        arg[h][u] = fmaxf(s0, 0.2f * s0);
        arg[h][4 + u] = fmaxf(s1, 0.2f * s1);
      }
    }
#pragma unroll
    for (int f = 0; f < CF; ++f) {
      f32x4 c0v = *(const f32x4*)&cfT[f * NN + jq];
      f32x4 c1v = *(const f32x4*)&cfT[f * NN + jq + 4];
      float dd[8];
#pragma unroll
      for (int u = 0; u < 4; ++u) {
        dd[u] = cfi[f] - c0v[u];
        dd[4 + u] = cfi[f] - c1v[u];
      }
#pragma unroll
      for (int h = 0; h < 4; ++h)
#pragma unroll
        for (int tt = 0; tt < 8; ++tt)
          arg[h][tt] = fmaf(fabsf(dd[tt]), wc[h][f], arg[h][tt]);  // abs folds into fma
    }
#pragma unroll
    for (int h = 0; h < 4; ++h) {
      bf16x8 af;
#pragma unroll
      for (int tt = 0; tt < 8; ++tt) {
        float pv = EXP2F(arg[h][tt]) * mf[tt];
        S[h] += pv;
        af[tt] = (bf16_t)pv;
      }
      const bf16_t* bp = hTbase + (size_t)h * ((NN / 32) * 1024) + c * 1024;
      bf16x8 b0 = *(const bf16x8*)bp;            // d = il
      bf16x8 b1 = *(const bf16x8*)(bp + 128);    // d = il + 16
      acc[h][0] = __builtin_amdgcn_mfma_f32_16x16x32_bf16(af, b0, acc[h][0], 0, 0, 0);
      acc[h][1] = __builtin_amdgcn_mfma_f32_16x16x32_bf16(af, b1, acc[h][1], 0, 0, 0);
    }
  }

  // reduce S across quads (lanes il, il+16, il+32, il+48)
#pragma unroll
  for (int h = 0; h < 4; ++h) {
    float v = S[h];
    v += __shfl_xor(v, 16, 64);
    v += __shfl_xor(v, 32, 64);
    S[h] = v;
  }
  if (quad == 0) {
#pragma unroll
    for (int h = 0; h < 4; ++h) atomicAdd(&Sbuf[il][h], S[h]);
  }
  // accumulate O partials: C/D layout row = quad*4+r (i), col = il (d half)
#pragma unroll
  for (int h = 0; h < 4; ++h)
#pragma unroll
    for (int dh = 0; dh < 2; ++dh)
#pragma unroll
      for (int r = 0; r < 4; ++r)
        atomicAdd(&Obuf[quad * 4 + r][h * DC + dh * 16 + il], acc[h][dh][r]);
  __syncthreads();

  // epilogue: divide by softmax denom, coalesced store
  for (int idx = tid; idx < 16 * 128; idx += 512) {
    int row = idx >> 7;
    int colg = idx & 127;
    out[(size_t)(ibase + row) * OC + hg * 128 + colg] =
        Obuf[row][colg] / Sbuf[row][colg >> 5];
  }
}

// ---------------------------------------------------------------------------
extern "C" void kernel_launch(void* const* d_in, const int* in_sizes, int n_in,
                              void* d_out, int out_size, void* d_ws, size_t ws_size,
                              hipStream_t stream) {
  const float* x    = (const float*)d_in[0];
  // d_in[1] = positions — unused by the reference
  const float* cfeat= (const float*)d_in[2];
  const int*   adj  = (const int*)d_in[3];
  const float* W    = (const float*)d_in[4];
  const float* a_l  = (const float*)d_in[5];
  const float* a_r  = (const float*)d_in[6];
  const float* Wc   = (const float*)d_in[7];
  const float* gate = (const float*)d_in[8];
  float* out = (float*)d_out;

  char* ws = (char*)d_ws;
  bf16_t*   hT2  = (bf16_t*)ws;                              // 2 MB
  unsigned* adjb = (unsigned*)(ws + (2u << 20));             // 2 MB
  float*    e_l2 = (float*)(ws + (4u << 20));                // 128 KB
  float*    e_r2T= (float*)(ws + (4u << 20) + (128u << 10)); // 128 KB
  float*    cfT  = (float*)(ws + (4u << 20) + (256u << 10)); // 96 KB
  float*    Wc2  = (float*)(ws + (4u << 20) + (384u << 10)); // 192 B

  gemm_fused<<<dim3(NN / 64, HC), 256, 0, stream>>>(x, W, a_l, a_r, e_l2, e_r2T, hT2);
  pack<<<2048, 256, 0, stream>>>(adj, cfeat, Wc, gate, adjb, cfT, Wc2);
  attn<<<dim3(NN / 16, 2), 512, 0, stream>>>(adjb, e_l2, e_r2T, cfT, Wc2, hT2, out);
}

// Round 4
// 247.792 us; speedup vs baseline: 1.8892x; 1.0198x over previous
//
#include <hip/hip_runtime.h>

#define NN 4096     // nodes
#define HC 8        // heads
#define DC 32       // dim per head
#define OC 256      // out channels = HC*DC
#define KC 256      // in channels
#define CF 6        // curvature features

typedef __bf16 bf16_t;
typedef bf16_t bf16x8 __attribute__((ext_vector_type(8)));
typedef float f32x4 __attribute__((ext_vector_type(4)));
typedef float f32x2 __attribute__((ext_vector_type(2)));
typedef int i32x4 __attribute__((ext_vector_type(4)));

#if defined(__has_builtin)
#if __has_builtin(__builtin_amdgcn_exp2f)
#define EXP2F(x) __builtin_amdgcn_exp2f(x)
#else
#define EXP2F(x) exp2f(x)
#endif
#else
#define EXP2F(x) exp2f(x)
#endif

static __device__ __forceinline__ f32x2 lo2(f32x4 v) { return __builtin_shufflevector(v, v, 0, 1); }
static __device__ __forceinline__ f32x2 hi2(f32x4 v) { return __builtin_shufflevector(v, v, 2, 3); }

// ---------------------------------------------------------------------------
// Kernel 1: heterogeneous prep. Blocks 0..511: fused h-GEMM (64i x 1 head)
// + e_l/e_r dots + bf16 B-fragment-layout V store (hT2). Blocks 512..2559:
// ballot-pack adj -> 2MB bitmask, cfT transpose, Wc2 precompute.
// Merging lets the HBM-bound pack overlap the compute-bound gemm across CUs
// and drops one launch.
// ---------------------------------------------------------------------------
__global__ __launch_bounds__(256) void prep_all(const float* __restrict__ x,
                                                const float* __restrict__ W,
                                                const float* __restrict__ a_l,
                                                const float* __restrict__ a_r,
                                                const int* __restrict__ adj,
                                                const float* __restrict__ cfeat,
                                                const float* __restrict__ Wc,
                                                const float* __restrict__ gate,
                                                float* __restrict__ e_l2,
                                                float* __restrict__ e_r2T,
                                                bf16_t* __restrict__ hT2,
                                                unsigned* __restrict__ adjb,
                                                float* __restrict__ cfT,
                                                float* __restrict__ Wc2) {
  __shared__ float As[16][68];   // [k][i]
  __shared__ float Bs[16][36];   // [k][c]
  __shared__ float Ct[DC][65];   // [c][i]
  const float LOG2E = 1.44269504088896340736f;
  const int t = threadIdx.x;
  const int bid = blockIdx.x;

  if (bid >= 512) {
    // ---------------- pack role ----------------
    const int pb = bid - 512;                    // 0..2047
    const int ptid = pb * 256 + t;
    const int lane = t & 63;
    const int wv = pb * 4 + (t >> 6);            // 0..8191
    for (int it = 0; it < 32; ++it) {
      int g = wv * 32 + it;                      // segment id
      int i = g >> 6;
      int s = g & 63;
      int v = adj[(size_t)i * NN + s * 64 + lane];
      unsigned long long m = __ballot(v > 0);
      if (lane == 0) *(unsigned long long*)(adjb + i * 128 + s * 2) = m;
    }
    if (ptid < NN * CF) {
      int j = ptid / CF, f = ptid - j * CF;
      cfT[f * NN + j] = cfeat[ptid];
    }
    if (ptid < HC * CF) Wc2[ptid] = Wc[ptid] * gate[0] * LOG2E;
    return;
  }

  // ---------------- gemm role ----------------
  const int i0 = (bid & 63) * 64;
  const int head = bid >> 6;
  const int c0 = head * DC;
  const int tx = t & 7;          // col group (4 cols)
  const int ty = t >> 3;         // row pair (2 rows)
  const int lr = t >> 2;         // staging row 0..63
  const int lk = (t & 3) * 4;    // staging k 0,4,8,12

  float acc[2][4] = {};
  for (int kk = 0; kk < KC; kk += 16) {
    f32x4 av = *(const f32x4*)&x[(size_t)(i0 + lr) * KC + kk + lk];
    f32x4 wv;
    if (t < 128) wv = *(const f32x4*)&W[(size_t)(c0 + (t >> 2)) * KC + kk + lk];
    __syncthreads();
    As[lk + 0][lr] = av[0]; As[lk + 1][lr] = av[1];
    As[lk + 2][lr] = av[2]; As[lk + 3][lr] = av[3];
    if (t < 128) {
      int br = t >> 2;
      Bs[lk + 0][br] = wv[0]; Bs[lk + 1][br] = wv[1];
      Bs[lk + 2][br] = wv[2]; Bs[lk + 3][br] = wv[3];
    }
    __syncthreads();
#pragma unroll
    for (int k = 0; k < 16; ++k) {
      f32x2 a = *(const f32x2*)&As[k][ty * 2];
      f32x4 b = *(const f32x4*)&Bs[k][tx * 4];
#pragma unroll
      for (int r = 0; r < 2; ++r)
#pragma unroll
        for (int u = 0; u < 4; ++u)
          acc[r][u] += a[r] * b[u];
    }
  }

  // e_l / e_r dots, reduce across the 8 tx lanes
  f32x4 al4 = *(const f32x4*)&a_l[c0 + tx * 4];
  f32x4 ar4 = *(const f32x4*)&a_r[c0 + tx * 4];
#pragma unroll
  for (int r = 0; r < 2; ++r) {
    float el = acc[r][0] * al4[0] + acc[r][1] * al4[1] +
               acc[r][2] * al4[2] + acc[r][3] * al4[3];
    float er = acc[r][0] * ar4[0] + acc[r][1] * ar4[1] +
               acc[r][2] * ar4[2] + acc[r][3] * ar4[3];
    el += __shfl_xor(el, 1, 64); el += __shfl_xor(el, 2, 64); el += __shfl_xor(el, 4, 64);
    er += __shfl_xor(er, 1, 64); er += __shfl_xor(er, 2, 64); er += __shfl_xor(er, 4, 64);
    if (tx == 0) {
      int i = i0 + ty * 2 + r;
      e_l2[i * HC + head] = el * LOG2E;
      e_r2T[head * NN + i] = er * LOG2E;
    }
  }

  // transpose to B-fragment layout via LDS
#pragma unroll
  for (int r = 0; r < 2; ++r)
#pragma unroll
    for (int u = 0; u < 4; ++u)
      Ct[tx * 4 + u][ty * 2 + r] = acc[r][u];
  __syncthreads();
  const size_t base = (size_t)head * (NN / 32) * 1024 + (size_t)(bid & 63) * 2048;
#pragma unroll
  for (int rep = 0; rep < 8; ++rep) {
    int idx = rep * 256 + t;                 // enumerates [chunkL][q][d][t8]
    int dd = (idx >> 3) & 31;
    int jl = (idx >> 10) * 32 + ((idx >> 8) & 3) * 8 + (idx & 7);
    hT2[base + idx] = (bf16_t)Ct[dd][jl];
  }
}

// ---------------------------------------------------------------------------
// Kernel 2: fused masked attention, 4 heads per block.
// Grid: (NN/16, 2) = 512 blocks x 512 threads (8 waves) -> 2 blocks/CU,
// 16 waves/CU (register-quantized; 3rd block needs <=85 regs -> spills).
// Inner math written on float2 so the backend emits packed fp32 VOP3P
// (v_pk_fma_f32 / v_pk_add_f32 / v_pk_max_f32): ~25% fewer issue slots,
// |dd| folds into one pk_max(dd,-dd). No online max (logits bounded, masked
// p == 0 exactly after exp2 underflow) so j-chunks combine by addition.
// ---------------------------------------------------------------------------
__global__ __launch_bounds__(512, 4) void attn(const unsigned* __restrict__ adjb,
                                               const float* __restrict__ e_l2,
                                               const float* __restrict__ e_r2T,
                                               const float* __restrict__ cfT,
                                               const float* __restrict__ Wc2,
                                               const bf16_t* __restrict__ hT2,
                                               float* __restrict__ out) {
  __shared__ float Obuf[16][128];
  __shared__ float Sbuf[16][4];
  const int tid = threadIdx.x;
  const int w = tid >> 6;        // 0..7
  const int lane = tid & 63;
  const int il = lane & 15;
  const int quad = lane >> 4;
  const int ibase = blockIdx.x * 16;
  const int hg = blockIdx.y;     // head group: heads hg*4 .. hg*4+3
  const int i = ibase + il;

  for (int idx = tid; idx < 16 * 128; idx += 512) (&Obuf[0][0])[idx] = 0.f;
  if (tid < 64) (&Sbuf[0][0])[tid] = 0.f;
  __syncthreads();

  f32x2 cfi2[CF];
#pragma unroll
  for (int f = 0; f < CF; ++f) { float v = cfT[f * NN + i]; cfi2[f] = (f32x2){v, v}; }
  f32x2 el2[4];
  {
    f32x4 e0 = *(const f32x4*)&e_l2[i * HC + hg * 4];
#pragma unroll
    for (int u = 0; u < 4; ++u) el2[u] = (f32x2){e0[u], e0[u]};
  }
  float wc[4][CF];
#pragma unroll
  for (int h = 0; h < 4; ++h)
#pragma unroll
    for (int f = 0; f < CF; ++f) wc[h][f] = Wc2[(hg * 4 + h) * CF + f];

  f32x4 acc[4][2];
#pragma unroll
  for (int h = 0; h < 4; ++h)
#pragma unroll
    for (int d = 0; d < 2; ++d) acc[h][d] = (f32x4){0.f, 0.f, 0.f, 0.f};
  f32x2 S2[4];
#pragma unroll
  for (int h = 0; h < 4; ++h) S2[h] = (f32x2){0.f, 0.f};

  const bf16_t* hTbase = hT2 + (size_t)hg * 4 * ((NN / 32) * 1024) + quad * 256 + il * 8;

  for (int c = w; c < NN / 32; c += 8) {
    const int jq = c * 32 + quad * 8;
    const unsigned m8 = (adjb[i * 128 + c] >> (quad * 8)) & 0xffu;

    // arg[h][p] over tt-pairs p (packed f32x2): leaky(el+er), then bias fmas
    f32x2 arg[4][4];
#pragma unroll
    for (int h = 0; h < 4; ++h) {
      f32x4 er0 = *(const f32x4*)&e_r2T[(hg * 4 + h) * NN + jq];
      f32x4 er1 = *(const f32x4*)&e_r2T[(hg * 4 + h) * NN + jq + 4];
      f32x2 ep[4] = {lo2(er0), hi2(er0), lo2(er1), hi2(er1)};
#pragma unroll
      for (int p = 0; p < 4; ++p) {
        f32x2 s = el2[h] + ep[p];
        arg[h][p] = __builtin_elementwise_max(s, 0.2f * s);
      }
    }
#pragma unroll
    for (int f = 0; f < CF; ++f) {
      f32x4 c0v = *(const f32x4*)&cfT[f * NN + jq];
      f32x4 c1v = *(const f32x4*)&cfT[f * NN + jq + 4];
      f32x2 cj[4] = {lo2(c0v), hi2(c0v), lo2(c1v), hi2(c1v)};
#pragma unroll
      for (int p = 0; p < 4; ++p) {
        f32x2 d2 = cfi2[f] - cj[p];
        f32x2 ab = __builtin_elementwise_max(d2, -d2);  // v_pk_max with neg mod
#pragma unroll
        for (int h = 0; h < 4; ++h) {
          f32x2 wsp = (f32x2){wc[h][f], wc[h][f]};
          arg[h][p] = __builtin_elementwise_fma(ab, wsp, arg[h][p]);
        }
      }
    }

    // mask bits -> float pairs
    f32x2 mf2[4];
#pragma unroll
    for (int p = 0; p < 4; ++p) {
      mf2[p] = (f32x2){(float)((m8 >> (2 * p)) & 1u), (float)((m8 >> (2 * p + 1)) & 1u)};
    }

#pragma unroll
    for (int h = 0; h < 4; ++h) {
      bf16x8 af;
#pragma unroll
      for (int p = 0; p < 4; ++p) {
        f32x2 pv = (f32x2){EXP2F(arg[h][p][0]), EXP2F(arg[h][p][1])};
        pv = pv * mf2[p];          // v_pk_mul
        S2[h] += pv;               // v_pk_add
        af[2 * p] = (bf16_t)pv[0];
        af[2 * p + 1] = (bf16_t)pv[1];
      }
      const bf16_t* bp = hTbase + (size_t)h * ((NN / 32) * 1024) + c * 1024;
      bf16x8 b0 = *(const bf16x8*)bp;            // d = il
      bf16x8 b1 = *(const bf16x8*)(bp + 128);    // d = il + 16
      acc[h][0] = __builtin_amdgcn_mfma_f32_16x16x32_bf16(af, b0, acc[h][0], 0, 0, 0);
      acc[h][1] = __builtin_amdgcn_mfma_f32_16x16x32_bf16(af, b1, acc[h][1], 0, 0, 0);
    }
  }

  // reduce S across quads (lanes il, il+16, il+32, il+48)
#pragma unroll
  for (int h = 0; h < 4; ++h) {
    float v = S2[h][0] + S2[h][1];
    v += __shfl_xor(v, 16, 64);
    v += __shfl_xor(v, 32, 64);
    if (quad == 0) atomicAdd(&Sbuf[il][h], v);
  }
  // accumulate O partials: C/D layout row = quad*4+r (i), col = il (d half)
#pragma unroll
  for (int h = 0; h < 4; ++h)
#pragma unroll
    for (int dh = 0; dh < 2; ++dh)
#pragma unroll
      for (int r = 0; r < 4; ++r)
        atomicAdd(&Obuf[quad * 4 + r][h * DC + dh * 16 + il], acc[h][dh][r]);
  __syncthreads();

  // epilogue: divide by softmax denom, coalesced store
  for (int idx = tid; idx < 16 * 128; idx += 512) {
    int row = idx >> 7;
    int colg = idx & 127;
    out[(size_t)(ibase + row) * OC + hg * 128 + colg] =
        Obuf[row][colg] / Sbuf[row][colg >> 5];
  }
}

// ---------------------------------------------------------------------------
extern "C" void kernel_launch(void* const* d_in, const int* in_sizes, int n_in,
                              void* d_out, int out_size, void* d_ws, size_t ws_size,
                              hipStream_t stream) {
  const float* x    = (const float*)d_in[0];
  // d_in[1] = positions — unused by the reference
  const float* cfeat= (const float*)d_in[2];
  const int*   adj  = (const int*)d_in[3];
  const float* W    = (const float*)d_in[4];
  const float* a_l  = (const float*)d_in[5];
  const float* a_r  = (const float*)d_in[6];
  const float* Wc   = (const float*)d_in[7];
  const float* gate = (const float*)d_in[8];
  float* out = (float*)d_out;

  char* ws = (char*)d_ws;
  bf16_t*   hT2  = (bf16_t*)ws;                              // 2 MB
  unsigned* adjb = (unsigned*)(ws + (2u << 20));             // 2 MB
  float*    e_l2 = (float*)(ws + (4u << 20));                // 128 KB
  float*    e_r2T= (float*)(ws + (4u << 20) + (128u << 10)); // 128 KB
  float*    cfT  = (float*)(ws + (4u << 20) + (256u << 10)); // 96 KB
  float*    Wc2  = (float*)(ws + (4u << 20) + (384u << 10)); // 192 B

  prep_all<<<2560, 256, 0, stream>>>(x, W, a_l, a_r, adj, cfeat, Wc, gate,
                                     e_l2, e_r2T, hT2, adjb, cfT, Wc2);
  attn<<<dim3(NN / 16, 2), 512, 0, stream>>>(adjb, e_l2, e_r2T, cfT, Wc2, hT2, out);
}